// Round 1
// baseline (52.781 us; speedup 1.0000x reference)
//
#include <hip/hip_runtime.h>
#include <math.h>

#define C   256
#define FC  256
#define H   32
#define W   32
#define HW  1024          // 32*32
#define KH  7
#define KW  7
#define PAD 3
#define KK  49

// ---------------------------------------------------------------------------
// Kernel A: fused q/k/v projection.
//   q[b,f,hw] = sum_c x[b,c,hw] * Wq[c,f]   (same for k,v)
// Block: 256 threads; tile 64 pixels (from tx) x 64 channels (from ty),
// each thread computes 4px x 4f for each of the 3 outputs.
// ---------------------------------------------------------------------------
__global__ __launch_bounds__(256) void qkv_proj_kernel(
    const float* __restrict__ x,  const float* __restrict__ Wq,
    const float* __restrict__ Wk, const float* __restrict__ Wv,
    float* __restrict__ q, float* __restrict__ k, float* __restrict__ v)
{
    __shared__ float xs [32][64];
    __shared__ float wqs[32][64];
    __shared__ float wks[32][64];
    __shared__ float wvs[32][64];

    const int b   = blockIdx.z;
    const int p0  = blockIdx.x * 64;   // pixel tile base (within batch)
    const int f0  = blockIdx.y * 64;   // channel tile base
    const int tid = threadIdx.x;
    const int tx  = tid & 15;          // pixel group   (4 px each)
    const int ty  = tid >> 4;          // channel group (4 f each)

    float aq[16], ak[16], av[16];
    #pragma unroll
    for (int i = 0; i < 16; ++i) { aq[i] = 0.f; ak[i] = 0.f; av[i] = 0.f; }

    const float* xb = x + (size_t)b * C * HW;

    for (int c0 = 0; c0 < C; c0 += 32) {
        #pragma unroll
        for (int i = 0; i < 8; ++i) {
            int idx = tid + i * 256;          // 0..2047
            int cc = idx >> 6, pp = idx & 63;
            xs [cc][pp] = xb[(size_t)(c0 + cc) * HW + p0 + pp];
            wqs[cc][pp] = Wq[(size_t)(c0 + cc) * FC + f0 + pp];
            wks[cc][pp] = Wk[(size_t)(c0 + cc) * FC + f0 + pp];
            wvs[cc][pp] = Wv[(size_t)(c0 + cc) * FC + f0 + pp];
        }
        __syncthreads();

        #pragma unroll
        for (int kk = 0; kk < 32; ++kk) {
            float4 xa = *(const float4*)&xs [kk][tx * 4];
            float4 q4 = *(const float4*)&wqs[kk][ty * 4];
            float4 k4 = *(const float4*)&wks[kk][ty * 4];
            float4 v4 = *(const float4*)&wvs[kk][ty * 4];
            float xr[4] = {xa.x, xa.y, xa.z, xa.w};
            float qr[4] = {q4.x, q4.y, q4.z, q4.w};
            float kr[4] = {k4.x, k4.y, k4.z, k4.w};
            float vr[4] = {v4.x, v4.y, v4.z, v4.w};
            #pragma unroll
            for (int j = 0; j < 4; ++j) {
                #pragma unroll
                for (int i = 0; i < 4; ++i) {
                    aq[j * 4 + i] = fmaf(qr[j], xr[i], aq[j * 4 + i]);
                    ak[j * 4 + i] = fmaf(kr[j], xr[i], ak[j * 4 + i]);
                    av[j * 4 + i] = fmaf(vr[j], xr[i], av[j * 4 + i]);
                }
            }
        }
        __syncthreads();
    }

    #pragma unroll
    for (int j = 0; j < 4; ++j) {
        int f = f0 + ty * 4 + j;
        size_t off = ((size_t)b * FC + f) * HW + p0 + tx * 4;
        *(float4*)&q[off] = make_float4(aq[j*4+0], aq[j*4+1], aq[j*4+2], aq[j*4+3]);
        *(float4*)&k[off] = make_float4(ak[j*4+0], ak[j*4+1], ak[j*4+2], ak[j*4+3]);
        *(float4*)&v[off] = make_float4(av[j*4+0], av[j*4+1], av[j*4+2], av[j*4+3]);
    }
}

// ---------------------------------------------------------------------------
// Kernel B: per-channel windowed softmax attention.
// Block = 256 threads = one 16x16 pixel tile for one (b, f).
// LDS: 22x22 zero-padded halo tiles of k and v + 49 rel values.
// Each thread: 49 scores in registers, max-sub softmax, weighted v-sum.
// Padded (out-of-image) positions participate with k=v=0 (matches ref).
// ---------------------------------------------------------------------------
__global__ __launch_bounds__(256) void attn_kernel(
    const float* __restrict__ q, const float* __restrict__ k,
    const float* __restrict__ v,
    const float* __restrict__ rel_x, const float* __restrict__ rel_y,
    const float* __restrict__ bias, float* __restrict__ out)
{
    __shared__ float ks[22][22];
    __shared__ float vs[22][22];
    __shared__ float rel_s[KK];

    const int b   = blockIdx.z;
    const int f   = blockIdx.y;
    const int th0 = (blockIdx.x >> 1) * 16;
    const int tw0 = (blockIdx.x & 1) * 16;
    const int tid = threadIdx.x;
    const int tx  = tid & 15;
    const int ty  = tid >> 4;

    if (tid < KK) {
        int dy = tid / KW, dx = tid % KW;
        rel_s[tid] = (f < 128) ? rel_x[dx * 128 + f]
                               : rel_y[dy * 128 + (f - 128)];
    }

    const float* kb = k + ((size_t)b * FC + f) * HW;
    const float* vb = v + ((size_t)b * FC + f) * HW;
    for (int i = tid; i < 22 * 22; i += 256) {
        int r = i / 22, c2 = i % 22;
        int hh = th0 - PAD + r;
        int ww = tw0 - PAD + c2;
        bool in = (hh >= 0) & (hh < H) & (ww >= 0) & (ww < W);
        ks[r][c2] = in ? kb[hh * W + ww] : 0.f;
        vs[r][c2] = in ? vb[hh * W + ww] : 0.f;
    }
    __syncthreads();

    const int hh = th0 + ty, ww = tw0 + tx;
    const float qv = q[((size_t)b * FC + f) * HW + hh * W + ww];

    float t[KK];
    float m = -INFINITY;
    #pragma unroll
    for (int ki = 0; ki < KK; ++ki) {
        int dy = ki / KW, dx = ki % KW;
        float s = qv * (ks[ty + dy][tx + dx] + rel_s[ki]);
        t[ki] = s;
        m = fmaxf(m, s);
    }

    float sum = 0.f, acc = 0.f;
    #pragma unroll
    for (int ki = 0; ki < KK; ++ki) {
        int dy = ki / KW, dx = ki % KW;
        float e = __expf(t[ki] - m);
        sum += e;
        acc = fmaf(e, vs[ty + dy][tx + dx], acc);
    }

    out[((size_t)b * FC + f) * HW + hh * W + ww] = acc / sum + bias[f];
}

// ---------------------------------------------------------------------------
extern "C" void kernel_launch(void* const* d_in, const int* in_sizes, int n_in,
                              void* d_out, int out_size, void* d_ws, size_t ws_size,
                              hipStream_t stream)
{
    const float* x     = (const float*)d_in[0];
    const float* Wq    = (const float*)d_in[1];
    const float* Wk    = (const float*)d_in[2];
    const float* Wv    = (const float*)d_in[3];
    const float* rel_x = (const float*)d_in[4];
    const float* rel_y = (const float*)d_in[5];
    const float* bias  = (const float*)d_in[6];
    float* out = (float*)d_out;

    const size_t plane = (size_t)4 * FC * HW; // 1M floats = 4 MB
    float* q = (float*)d_ws;
    float* k = q + plane;
    float* v = k + plane;

    dim3 pgrid(HW / 64, FC / 64, 4);          // 16 x 4 x 4 = 256 blocks
    qkv_proj_kernel<<<pgrid, 256, 0, stream>>>(x, Wq, Wk, Wv, q, k, v);

    dim3 agrid(4, FC, 4);                     // 4 tiles x 256 f x 4 b
    attn_kernel<<<agrid, 256, 0, stream>>>(q, k, v, rel_x, rel_y, bias, out);
}

// Round 2
// 37.562 us; speedup vs baseline: 1.4051x; 1.4051x over previous
//
#include <hip/hip_runtime.h>
#include <math.h>

#define C   256
#define FC  256
#define H   32
#define W   32
#define HW  1024
#define KH  7
#define KW  7
#define PAD 3
#define KK  49

typedef short s16x8 __attribute__((ext_vector_type(8)));
typedef float f32x4 __attribute__((ext_vector_type(4)));

__device__ __forceinline__ ushort f2bf(float f) {
    uint u = __float_as_uint(f);
    u += 0x7FFFu + ((u >> 16) & 1u);       // round-to-nearest-even
    return (ushort)(u >> 16);
}
__device__ __forceinline__ float bf2f(ushort u) {
    return __uint_as_float(((uint)u) << 16);
}

// ---------------------------------------------------------------------------
// Kernel 0: transpose+convert.
//   x (b,c,px) f32  -> Xt (b,px,c) bf16      [blocks 0..255]
//   W (c,f)    f32  -> Wt (mat,f,c) bf16     [blocks 256..303]
// Reads coalesced (lane = col); writes 8B chunks, L2 merges lines.
// ---------------------------------------------------------------------------
__global__ __launch_bounds__(256) void prep_kernel(
    const float* __restrict__ x, const float* __restrict__ Wq,
    const float* __restrict__ Wk, const float* __restrict__ Wv,
    ushort* __restrict__ Xt, ushort* __restrict__ Wt)
{
    const int id = blockIdx.x;
    const float* src; ushort* dst; int sstride;
    if (id < 256) {
        int b = id >> 6, pxt = (id >> 2) & 15, ct = id & 3;
        src = x + ((size_t)(b * C + ct * 64)) * HW + pxt * 64;
        sstride = HW;
        dst = Xt + ((size_t)(b * HW + pxt * 64)) * C + ct * 64;
    } else {
        int wid = id - 256;
        int mat = wid >> 4, ft = (wid >> 2) & 3, ct = wid & 3;
        const float* Ws = (mat == 0) ? Wq : (mat == 1) ? Wk : Wv;
        src = Ws + ((size_t)(ct * 64)) * FC + ft * 64;
        sstride = FC;
        dst = Wt + ((size_t)(mat * FC + ft * 64)) * C + ct * 64;
    }
    const int t   = threadIdx.x;
    const int col = t & 63;      // src col = dst row
    const int rq  = t >> 6;      // src row quad (16 rows each)
    ushort tmp[16];
    #pragma unroll
    for (int i = 0; i < 16; ++i)
        tmp[i] = f2bf(src[(size_t)(rq * 16 + i) * sstride + col]);
    #pragma unroll
    for (int i = 0; i < 4; ++i) {
        ushort4 u = make_ushort4(tmp[i*4], tmp[i*4+1], tmp[i*4+2], tmp[i*4+3]);
        *(ushort4*)&dst[(size_t)col * C + rq * 16 + i * 4] = u;
    }
}

// ---------------------------------------------------------------------------
// Kernel 1: fused q/k/v projection via bf16 MFMA.
// Block 256 thr = 4 waves; tile 64f x 64px x 3 mats; grid 256 blocks (1/CU).
// Wave quadrant: 32f x 32px -> acc[3][2][2] 16x16 frags.
// X tile (64px x 256k) staged in LDS (pad 8 -> free 2-way bank alias);
// W frags read from global (Wt 384KB, L2-hot). 8 K-steps, sw-pipelined.
// ---------------------------------------------------------------------------
__global__ __launch_bounds__(256) void qkv_mfma_kernel(
    const ushort* __restrict__ Xt, const ushort* __restrict__ Wt,
    ushort* __restrict__ qo, ushort* __restrict__ ko, ushort* __restrict__ vo)
{
    __shared__ ushort Xs[64][264];
    const int t   = threadIdx.x;
    const int bid = blockIdx.x;
    const int ft  = bid & 3, pxt = (bid >> 2) & 15, b = bid >> 6;

    const ushort* Xtb = Xt + ((size_t)(b * HW + pxt * 64)) * C;
    #pragma unroll
    for (int i = 0; i < 8; ++i) {
        int idx = t + i * 256;
        int r = idx >> 5, c = idx & 31;
        *(s16x8*)&Xs[r][c * 8] = *(const s16x8*)&Xtb[(size_t)r * C + c * 8];
    }
    __syncthreads();

    const int wid = t >> 6, lane = t & 63;
    const int wf = wid >> 1, wp = wid & 1;
    const int lr = lane & 15, lk = (lane >> 4) * 8;
    const int fbase = ft * 64 + wf * 32;   // global f base of this wave
    const int pxb   = wp * 32;             // px base within tile

    f32x4 acc[3][2][2];
    #pragma unroll
    for (int m = 0; m < 3; ++m)
      #pragma unroll
      for (int i = 0; i < 2; ++i)
        #pragma unroll
        for (int j = 0; j < 2; ++j)
          acc[m][i][j] = (f32x4){0.f, 0.f, 0.f, 0.f};

    const ushort* wp0[3][2];
    #pragma unroll
    for (int m = 0; m < 3; ++m)
      #pragma unroll
      for (int fc = 0; fc < 2; ++fc)
        wp0[m][fc] = Wt + ((size_t)(m * FC + fbase + fc * 16 + lr)) * C + lk;

    s16x8 wfr[2][3][2], xfr[2][2];
    #pragma unroll
    for (int m = 0; m < 3; ++m)
      #pragma unroll
      for (int fc = 0; fc < 2; ++fc)
        wfr[0][m][fc] = *(const s16x8*)(wp0[m][fc]);
    #pragma unroll
    for (int pc = 0; pc < 2; ++pc)
      xfr[0][pc] = *(const s16x8*)&Xs[pxb + pc * 16 + lr][lk];

    #pragma unroll
    for (int kk = 0; kk < 8; ++kk) {
        const int cur = kk & 1, nxt = cur ^ 1;
        if (kk < 7) {
            const int k0 = (kk + 1) * 32;
            #pragma unroll
            for (int m = 0; m < 3; ++m)
              #pragma unroll
              for (int fc = 0; fc < 2; ++fc)
                wfr[nxt][m][fc] = *(const s16x8*)(wp0[m][fc] + k0);
            #pragma unroll
            for (int pc = 0; pc < 2; ++pc)
              xfr[nxt][pc] = *(const s16x8*)&Xs[pxb + pc * 16 + lr][k0 + lk];
        }
        #pragma unroll
        for (int m = 0; m < 3; ++m)
          #pragma unroll
          for (int fc = 0; fc < 2; ++fc)
            #pragma unroll
            for (int pc = 0; pc < 2; ++pc)
              acc[m][fc][pc] = __builtin_amdgcn_mfma_f32_16x16x32_bf16(
                  wfr[cur][m][fc], xfr[cur][pc], acc[m][fc][pc], 0, 0, 0);
    }

    const int fg = (lane >> 4) * 4;        // C/D: row=(lane>>4)*4+j, col=lane&15
    ushort* outs[3] = {qo, ko, vo};
    #pragma unroll
    for (int m = 0; m < 3; ++m)
      #pragma unroll
      for (int fc = 0; fc < 2; ++fc)
        #pragma unroll
        for (int pc = 0; pc < 2; ++pc)
          #pragma unroll
          for (int j = 0; j < 4; ++j) {
            int fr = fbase + fc * 16 + fg + j;
            int px = pxt * 64 + pxb + pc * 16 + lr;
            outs[m][((size_t)(b * FC + fr)) * HW + px] = f2bf(acc[m][fc][pc][j]);
          }
}

// ---------------------------------------------------------------------------
// Kernel 2: per-channel windowed softmax attention (q/k/v now bf16).
// ---------------------------------------------------------------------------
__global__ __launch_bounds__(256) void attn_kernel(
    const ushort* __restrict__ q, const ushort* __restrict__ k,
    const ushort* __restrict__ v,
    const float* __restrict__ rel_x, const float* __restrict__ rel_y,
    const float* __restrict__ bias, float* __restrict__ out)
{
    __shared__ float ks[22][22];
    __shared__ float vs[22][22];
    __shared__ float rel_s[KK];

    const int b   = blockIdx.z;
    const int f   = blockIdx.y;
    const int th0 = (blockIdx.x >> 1) * 16;
    const int tw0 = (blockIdx.x & 1) * 16;
    const int tid = threadIdx.x;
    const int tx  = tid & 15;
    const int ty  = tid >> 4;

    if (tid < KK) {
        int dy = tid / KW, dx = tid % KW;
        rel_s[tid] = (f < 128) ? rel_x[dx * 128 + f]
                               : rel_y[dy * 128 + (f - 128)];
    }

    const ushort* kb = k + ((size_t)b * FC + f) * HW;
    const ushort* vb = v + ((size_t)b * FC + f) * HW;
    for (int i = tid; i < 22 * 22; i += 256) {
        int r = i / 22, c2 = i % 22;
        int hh = th0 - PAD + r;
        int ww = tw0 - PAD + c2;
        bool in = (hh >= 0) & (hh < H) & (ww >= 0) & (ww < W);
        ks[r][c2] = in ? bf2f(kb[hh * W + ww]) : 0.f;
        vs[r][c2] = in ? bf2f(vb[hh * W + ww]) : 0.f;
    }
    __syncthreads();

    const int hh = th0 + ty, ww = tw0 + tx;
    const float qv = bf2f(q[((size_t)b * FC + f) * HW + hh * W + ww]);

    float tt[KK];
    float m = -INFINITY;
    #pragma unroll
    for (int ki = 0; ki < KK; ++ki) {
        int dy = ki / KW, dx = ki % KW;
        float s = qv * (ks[ty + dy][tx + dx] + rel_s[ki]);
        tt[ki] = s;
        m = fmaxf(m, s);
    }

    float sum = 0.f, acc = 0.f;
    #pragma unroll
    for (int ki = 0; ki < KK; ++ki) {
        int dy = ki / KW, dx = ki % KW;
        float e = __expf(tt[ki] - m);
        sum += e;
        acc = fmaf(e, vs[ty + dy][tx + dx], acc);
    }

    out[((size_t)b * FC + f) * HW + hh * W + ww] = acc / sum + bias[f];
}

// ---------------------------------------------------------------------------
extern "C" void kernel_launch(void* const* d_in, const int* in_sizes, int n_in,
                              void* d_out, int out_size, void* d_ws, size_t ws_size,
                              hipStream_t stream)
{
    const float* x     = (const float*)d_in[0];
    const float* Wq    = (const float*)d_in[1];
    const float* Wk    = (const float*)d_in[2];
    const float* Wv    = (const float*)d_in[3];
    const float* rel_x = (const float*)d_in[4];
    const float* rel_y = (const float*)d_in[5];
    const float* bias  = (const float*)d_in[6];
    float* out = (float*)d_out;

    ushort* Xt  = (ushort*)d_ws;                  // 4*1024*256 bf16 = 2 MB
    ushort* Wtp = Xt + (size_t)4 * HW * C;        // 3*256*256  bf16 = 384 KB
    ushort* q   = Wtp + (size_t)3 * FC * C;       // 2 MB each
    ushort* kk  = q + (size_t)4 * FC * HW;
    ushort* vv  = kk + (size_t)4 * FC * HW;

    prep_kernel<<<304, 256, 0, stream>>>(x, Wq, Wk, Wv, Xt, Wtp);
    qkv_mfma_kernel<<<256, 256, 0, stream>>>(Xt, Wtp, q, kk, vv);
    attn_kernel<<<dim3(4, FC, 4), 256, 0, stream>>>(q, kk, vv, rel_x, rel_y, bias, out);
}

// Round 3
// 37.337 us; speedup vs baseline: 1.4136x; 1.0060x over previous
//
#include <hip/hip_runtime.h>
#include <math.h>

#define C   256
#define FC  256
#define H   32
#define W   32
#define HW  1024
#define KH  7
#define KW  7
#define PAD 3
#define KK  49

typedef short s16x8 __attribute__((ext_vector_type(8)));
typedef float f32x4 __attribute__((ext_vector_type(4)));

__device__ __forceinline__ ushort f2bf(float f) {
    uint u = __float_as_uint(f);
    u += 0x7FFFu + ((u >> 16) & 1u);       // round-to-nearest-even
    return (ushort)(u >> 16);
}
__device__ __forceinline__ float bf2f(ushort u) {
    return __uint_as_float(((uint)u) << 16);
}

// ---------------------------------------------------------------------------
// Kernel 0: transpose+convert (unchanged from R2 — proven).
//   x (b,c,px) f32  -> Xt (b,px,c) bf16      [blocks 0..255]
//   W (c,f)    f32  -> Wt (mat,f,c) bf16     [blocks 256..303]
// ---------------------------------------------------------------------------
__global__ __launch_bounds__(256) void prep_kernel(
    const float* __restrict__ x, const float* __restrict__ Wq,
    const float* __restrict__ Wk, const float* __restrict__ Wv,
    ushort* __restrict__ Xt, ushort* __restrict__ Wt)
{
    const int id = blockIdx.x;
    const float* src; ushort* dst; int sstride;
    if (id < 256) {
        int b = id >> 6, pxt = (id >> 2) & 15, ct = id & 3;
        src = x + ((size_t)(b * C + ct * 64)) * HW + pxt * 64;
        sstride = HW;
        dst = Xt + ((size_t)(b * HW + pxt * 64)) * C + ct * 64;
    } else {
        int wid = id - 256;
        int mat = wid >> 4, ft = (wid >> 2) & 3, ct = wid & 3;
        const float* Ws = (mat == 0) ? Wq : (mat == 1) ? Wk : Wv;
        src = Ws + ((size_t)(ct * 64)) * FC + ft * 64;
        sstride = FC;
        dst = Wt + ((size_t)(mat * FC + ft * 64)) * C + ct * 64;
    }
    const int t   = threadIdx.x;
    const int col = t & 63;      // src col = dst row
    const int rq  = t >> 6;      // src row quad (16 rows each)
    ushort tmp[16];
    #pragma unroll
    for (int i = 0; i < 16; ++i)
        tmp[i] = f2bf(src[(size_t)(rq * 16 + i) * sstride + col]);
    #pragma unroll
    for (int i = 0; i < 4; ++i) {
        ushort4 u = make_ushort4(tmp[i*4], tmp[i*4+1], tmp[i*4+2], tmp[i*4+3]);
        *(ushort4*)&dst[(size_t)col * C + rq * 16 + i * 4] = u;
    }
}

// ---------------------------------------------------------------------------
// Kernel 1: fused q/k/v projection via bf16 MFMA, v2.
// Grid (16 pxt, 8 fg, 4 b) = 512 blocks = 2 blocks/CU (8 waves/CU, 2/SIMD).
// Block tile: 32f x 64px x 3 mats. Wave: 16f x 32px -> acc[3][2].
// X tile in LDS (pad 264 -> 2-way alias, free); W frags from global (L2-hot).
// ---------------------------------------------------------------------------
__global__ __launch_bounds__(256) void qkv_mfma_kernel(
    const ushort* __restrict__ Xt, const ushort* __restrict__ Wt,
    ushort* __restrict__ qo, ushort* __restrict__ ko, ushort* __restrict__ vo)
{
    __shared__ ushort Xs[64][264];
    const int t   = threadIdx.x;
    const int pxt = blockIdx.x;        // 0..15
    const int fg  = blockIdx.y;        // 0..7
    const int b   = blockIdx.z;        // 0..3

    const ushort* Xtb = Xt + ((size_t)(b * HW + pxt * 64)) * C;
    #pragma unroll
    for (int i = 0; i < 8; ++i) {
        int idx = t + i * 256;
        int r = idx >> 5, c = idx & 31;
        *(s16x8*)&Xs[r][c * 8] = *(const s16x8*)&Xtb[(size_t)r * C + c * 8];
    }
    __syncthreads();

    const int wid = t >> 6, lane = t & 63;
    const int wf = wid >> 1, wp = wid & 1;
    const int lr = lane & 15, lk = (lane >> 4) * 8;
    const int fbase = fg * 32 + wf * 16;   // global f base of this wave's frag
    const int pxb   = wp * 32;             // px base within tile

    f32x4 acc[3][2];
    #pragma unroll
    for (int m = 0; m < 3; ++m)
      #pragma unroll
      for (int pc = 0; pc < 2; ++pc)
        acc[m][pc] = (f32x4){0.f, 0.f, 0.f, 0.f};

    const ushort* ap[3];
    #pragma unroll
    for (int m = 0; m < 3; ++m)
        ap[m] = Wt + ((size_t)(m * FC + fbase + lr)) * C + lk;

    s16x8 af[2][3], xf[2][2];
    #pragma unroll
    for (int m = 0; m < 3; ++m) af[0][m] = *(const s16x8*)(ap[m]);
    #pragma unroll
    for (int pc = 0; pc < 2; ++pc)
        xf[0][pc] = *(const s16x8*)&Xs[pxb + pc * 16 + lr][lk];

    #pragma unroll
    for (int kk = 0; kk < 8; ++kk) {
        const int cur = kk & 1, nxt = cur ^ 1;
        if (kk < 7) {
            const int k0 = (kk + 1) * 32;
            #pragma unroll
            for (int m = 0; m < 3; ++m)
                af[nxt][m] = *(const s16x8*)(ap[m] + k0);
            #pragma unroll
            for (int pc = 0; pc < 2; ++pc)
                xf[nxt][pc] = *(const s16x8*)&Xs[pxb + pc * 16 + lr][k0 + lk];
        }
        #pragma unroll
        for (int m = 0; m < 3; ++m)
          #pragma unroll
          for (int pc = 0; pc < 2; ++pc)
            acc[m][pc] = __builtin_amdgcn_mfma_f32_16x16x32_bf16(
                af[cur][m], xf[cur][pc], acc[m][pc], 0, 0, 0);
    }

    const int fg4 = (lane >> 4) * 4;       // C/D: row=(lane>>4)*4+j, col=lane&15
    ushort* outs[3] = {qo, ko, vo};
    #pragma unroll
    for (int m = 0; m < 3; ++m)
      #pragma unroll
      for (int pc = 0; pc < 2; ++pc)
        #pragma unroll
        for (int j = 0; j < 4; ++j) {
            int fr = fbase + fg4 + j;
            int px = pxt * 64 + pxb + pc * 16 + lr;
            outs[m][((size_t)(b * FC + fr)) * HW + px] = f2bf(acc[m][pc][j]);
        }
}

// ---------------------------------------------------------------------------
// Kernel 2: per-channel windowed softmax attention (unchanged from R2).
// ---------------------------------------------------------------------------
__global__ __launch_bounds__(256) void attn_kernel(
    const ushort* __restrict__ q, const ushort* __restrict__ k,
    const ushort* __restrict__ v,
    const float* __restrict__ rel_x, const float* __restrict__ rel_y,
    const float* __restrict__ bias, float* __restrict__ out)
{
    __shared__ float ks[22][22];
    __shared__ float vs[22][22];
    __shared__ float rel_s[KK];

    const int b   = blockIdx.z;
    const int f   = blockIdx.y;
    const int th0 = (blockIdx.x >> 1) * 16;
    const int tw0 = (blockIdx.x & 1) * 16;
    const int tid = threadIdx.x;
    const int tx  = tid & 15;
    const int ty  = tid >> 4;

    if (tid < KK) {
        int dy = tid / KW, dx = tid % KW;
        rel_s[tid] = (f < 128) ? rel_x[dx * 128 + f]
                               : rel_y[dy * 128 + (f - 128)];
    }

    const ushort* kb = k + ((size_t)b * FC + f) * HW;
    const ushort* vb = v + ((size_t)b * FC + f) * HW;
    for (int i = tid; i < 22 * 22; i += 256) {
        int r = i / 22, c2 = i % 22;
        int hh = th0 - PAD + r;
        int ww = tw0 - PAD + c2;
        bool in = (hh >= 0) & (hh < H) & (ww >= 0) & (ww < W);
        ks[r][c2] = in ? bf2f(kb[hh * W + ww]) : 0.f;
        vs[r][c2] = in ? bf2f(vb[hh * W + ww]) : 0.f;
    }
    __syncthreads();

    const int hh = th0 + ty, ww = tw0 + tx;
    const float qv = bf2f(q[((size_t)b * FC + f) * HW + hh * W + ww]);

    float tt[KK];
    float m = -INFINITY;
    #pragma unroll
    for (int ki = 0; ki < KK; ++ki) {
        int dy = ki / KW, dx = ki % KW;
        float s = qv * (ks[ty + dy][tx + dx] + rel_s[ki]);
        tt[ki] = s;
        m = fmaxf(m, s);
    }

    float sum = 0.f, acc = 0.f;
    #pragma unroll
    for (int ki = 0; ki < KK; ++ki) {
        int dy = ki / KW, dx = ki % KW;
        float e = __expf(tt[ki] - m);
        sum += e;
        acc = fmaf(e, vs[ty + dy][tx + dx], acc);
    }

    out[((size_t)b * FC + f) * HW + hh * W + ww] = acc / sum + bias[f];
}

// ---------------------------------------------------------------------------
extern "C" void kernel_launch(void* const* d_in, const int* in_sizes, int n_in,
                              void* d_out, int out_size, void* d_ws, size_t ws_size,
                              hipStream_t stream)
{
    const float* x     = (const float*)d_in[0];
    const float* Wq    = (const float*)d_in[1];
    const float* Wk    = (const float*)d_in[2];
    const float* Wv    = (const float*)d_in[3];
    const float* rel_x = (const float*)d_in[4];
    const float* rel_y = (const float*)d_in[5];
    const float* bias  = (const float*)d_in[6];
    float* out = (float*)d_out;

    ushort* Xt  = (ushort*)d_ws;                  // 4*1024*256 bf16 = 2 MB
    ushort* Wtp = Xt + (size_t)4 * HW * C;        // 3*256*256  bf16 = 384 KB
    ushort* q   = Wtp + (size_t)3 * FC * C;       // 2 MB each
    ushort* kk  = q + (size_t)4 * FC * HW;
    ushort* vv  = kk + (size_t)4 * FC * HW;

    prep_kernel<<<304, 256, 0, stream>>>(x, Wq, Wk, Wv, Xt, Wtp);
    qkv_mfma_kernel<<<dim3(16, 8, 4), 256, 0, stream>>>(Xt, Wtp, q, kk, vv);
    attn_kernel<<<dim3(4, FC, 4), 256, 0, stream>>>(q, kk, vv, rel_x, rel_y, bias, out);
}

// Round 4
// 37.120 us; speedup vs baseline: 1.4219x; 1.0059x over previous
//
#include <hip/hip_runtime.h>
#include <math.h>

#define C   256
#define FC  256
#define H   32
#define W   32
#define HW  1024
#define KH  7
#define KW  7
#define PAD 3
#define KK  49

typedef short s16x8 __attribute__((ext_vector_type(8)));
typedef float f32x4 __attribute__((ext_vector_type(4)));

__device__ __forceinline__ ushort f2bf(float f) {
    uint u = __float_as_uint(f);
    u += 0x7FFFu + ((u >> 16) & 1u);       // round-to-nearest-even
    return (ushort)(u >> 16);
}
__device__ __forceinline__ float bf2f(ushort u) {
    return __uint_as_float(((uint)u) << 16);
}

// ---------------------------------------------------------------------------
// Kernel 0: transpose+convert (unchanged — attribution control).
//   x (b,c,px) f32  -> Xt (b,px,c) bf16      [blocks 0..255]
//   W (c,f)    f32  -> Wt (mat,f,c) bf16     [blocks 256..303]
// ---------------------------------------------------------------------------
__global__ __launch_bounds__(256) void prep_kernel(
    const float* __restrict__ x, const float* __restrict__ Wq,
    const float* __restrict__ Wk, const float* __restrict__ Wv,
    ushort* __restrict__ Xt, ushort* __restrict__ Wt)
{
    const int id = blockIdx.x;
    const float* src; ushort* dst; int sstride;
    if (id < 256) {
        int b = id >> 6, pxt = (id >> 2) & 15, ct = id & 3;
        src = x + ((size_t)(b * C + ct * 64)) * HW + pxt * 64;
        sstride = HW;
        dst = Xt + ((size_t)(b * HW + pxt * 64)) * C + ct * 64;
    } else {
        int wid = id - 256;
        int mat = wid >> 4, ft = (wid >> 2) & 3, ct = wid & 3;
        const float* Ws = (mat == 0) ? Wq : (mat == 1) ? Wk : Wv;
        src = Ws + ((size_t)(ct * 64)) * FC + ft * 64;
        sstride = FC;
        dst = Wt + ((size_t)(mat * FC + ft * 64)) * C + ct * 64;
    }
    const int t   = threadIdx.x;
    const int col = t & 63;      // src col = dst row
    const int rq  = t >> 6;      // src row quad (16 rows each)
    ushort tmp[16];
    #pragma unroll
    for (int i = 0; i < 16; ++i)
        tmp[i] = f2bf(src[(size_t)(rq * 16 + i) * sstride + col]);
    #pragma unroll
    for (int i = 0; i < 4; ++i) {
        ushort4 u = make_ushort4(tmp[i*4], tmp[i*4+1], tmp[i*4+2], tmp[i*4+3]);
        *(ushort4*)&dst[(size_t)col * C + rq * 16 + i * 4] = u;
    }
}

// ---------------------------------------------------------------------------
// Kernel 1: fused q/k/v projection via bf16 MFMA, v3.
// Grid (16 pxt, 8 fg, 4 b) = 512 blocks (2/CU). Block: 32f x 64px x 3 mats.
// Wave: 16f x 32px -> 6 named f32x4 accumulators. NO runtime-indexed arrays
// (scratch hazard, rule #20). Xs unpadded [64][256] with XOR-swizzled 16B
// column groups (cg ^= row&7) -> optimal 8-cy ds_read_b128 / ds_write_b128.
// W frags stream from global (Wt = 384 KB, L2-hot).
// ---------------------------------------------------------------------------
__global__ __launch_bounds__(256) void qkv_mfma_kernel(
    const ushort* __restrict__ Xt, const ushort* __restrict__ Wt,
    ushort* __restrict__ qo, ushort* __restrict__ ko, ushort* __restrict__ vo)
{
    __shared__ ushort Xs[64][256];
    const int t   = threadIdx.x;
    const int pxt = blockIdx.x;        // 0..15
    const int fg  = blockIdx.y;        // 0..7
    const int b   = blockIdx.z;        // 0..3

    const ushort* Xtb = Xt + ((size_t)(b * HW + pxt * 64)) * C;
    #pragma unroll
    for (int i = 0; i < 8; ++i) {
        int idx = t + i * 256;
        int r = idx >> 5, c = idx & 31;           // row, 16B col-group
        *(s16x8*)&Xs[r][((c ^ (r & 7)) << 3)] =
            *(const s16x8*)&Xtb[(size_t)r * C + (c << 3)];
    }
    __syncthreads();

    const int wid = t >> 6, lane = t & 63;
    const int wf = wid >> 1, wp = wid & 1;
    const int lr = lane & 15;              // A: f row / B: px col
    const int g  = lane >> 4;              // k-group 0..3 (8 bf16 each)
    const int fbase = fg * 32 + wf * 16;
    const int pxb   = wp * 32;
    const int r7    = lr & 7;              // swizzle key (same for row, row+16)

    const ushort* a0p = Wt + ((size_t)(0 * FC + fbase + lr)) * C + g * 8;
    const ushort* a1p = Wt + ((size_t)(1 * FC + fbase + lr)) * C + g * 8;
    const ushort* a2p = Wt + ((size_t)(2 * FC + fbase + lr)) * C + g * 8;
    const ushort* xr0 = &Xs[pxb + lr][0];
    const ushort* xr1 = &Xs[pxb + 16 + lr][0];

    f32x4 acc00 = {0.f,0.f,0.f,0.f}, acc01 = {0.f,0.f,0.f,0.f};
    f32x4 acc10 = {0.f,0.f,0.f,0.f}, acc11 = {0.f,0.f,0.f,0.f};
    f32x4 acc20 = {0.f,0.f,0.f,0.f}, acc21 = {0.f,0.f,0.f,0.f};

    #pragma unroll
    for (int kk = 0; kk < 8; ++kk) {
        const int k0  = kk * 32;
        const int swo = ((kk * 4 + g) ^ r7) << 3;   // swizzled 16B group offset
        s16x8 a0 = *(const s16x8*)(a0p + k0);
        s16x8 a1 = *(const s16x8*)(a1p + k0);
        s16x8 a2 = *(const s16x8*)(a2p + k0);
        s16x8 b0 = *(const s16x8*)(xr0 + swo);
        s16x8 b1 = *(const s16x8*)(xr1 + swo);
        acc00 = __builtin_amdgcn_mfma_f32_16x16x32_bf16(a0, b0, acc00, 0, 0, 0);
        acc01 = __builtin_amdgcn_mfma_f32_16x16x32_bf16(a0, b1, acc01, 0, 0, 0);
        acc10 = __builtin_amdgcn_mfma_f32_16x16x32_bf16(a1, b0, acc10, 0, 0, 0);
        acc11 = __builtin_amdgcn_mfma_f32_16x16x32_bf16(a1, b1, acc11, 0, 0, 0);
        acc20 = __builtin_amdgcn_mfma_f32_16x16x32_bf16(a2, b0, acc20, 0, 0, 0);
        acc21 = __builtin_amdgcn_mfma_f32_16x16x32_bf16(a2, b1, acc21, 0, 0, 0);
    }

    const int fg4 = g * 4;                 // C/D: row=(lane>>4)*4+j, col=lane&15
    const int px0 = pxt * 64 + pxb + lr;
    #pragma unroll
    for (int j = 0; j < 4; ++j) {
        size_t ro = ((size_t)(b * FC + fbase + fg4 + j)) * HW + px0;
        qo[ro]      = f2bf(acc00[j]);
        qo[ro + 16] = f2bf(acc01[j]);
        ko[ro]      = f2bf(acc10[j]);
        ko[ro + 16] = f2bf(acc11[j]);
        vo[ro]      = f2bf(acc20[j]);
        vo[ro + 16] = f2bf(acc21[j]);
    }
}

// ---------------------------------------------------------------------------
// Kernel 2: per-channel windowed softmax attention (unchanged).
// ---------------------------------------------------------------------------
__global__ __launch_bounds__(256) void attn_kernel(
    const ushort* __restrict__ q, const ushort* __restrict__ k,
    const ushort* __restrict__ v,
    const float* __restrict__ rel_x, const float* __restrict__ rel_y,
    const float* __restrict__ bias, float* __restrict__ out)
{
    __shared__ float ks[22][22];
    __shared__ float vs[22][22];
    __shared__ float rel_s[KK];

    const int b   = blockIdx.z;
    const int f   = blockIdx.y;
    const int th0 = (blockIdx.x >> 1) * 16;
    const int tw0 = (blockIdx.x & 1) * 16;
    const int tid = threadIdx.x;
    const int tx  = tid & 15;
    const int ty  = tid >> 4;

    if (tid < KK) {
        int dy = tid / KW, dx = tid % KW;
        rel_s[tid] = (f < 128) ? rel_x[dx * 128 + f]
                               : rel_y[dy * 128 + (f - 128)];
    }

    const ushort* kb = k + ((size_t)b * FC + f) * HW;
    const ushort* vb = v + ((size_t)b * FC + f) * HW;
    for (int i = tid; i < 22 * 22; i += 256) {
        int r = i / 22, c2 = i % 22;
        int hh = th0 - PAD + r;
        int ww = tw0 - PAD + c2;
        bool in = (hh >= 0) & (hh < H) & (ww >= 0) & (ww < W);
        ks[r][c2] = in ? bf2f(kb[hh * W + ww]) : 0.f;
        vs[r][c2] = in ? bf2f(vb[hh * W + ww]) : 0.f;
    }
    __syncthreads();

    const int hh = th0 + ty, ww = tw0 + tx;
    const float qv = bf2f(q[((size_t)b * FC + f) * HW + hh * W + ww]);

    float tt[KK];
    float m = -INFINITY;
    #pragma unroll
    for (int ki = 0; ki < KK; ++ki) {
        int dy = ki / KW, dx = ki % KW;
        float s = qv * (ks[ty + dy][tx + dx] + rel_s[ki]);
        tt[ki] = s;
        m = fmaxf(m, s);
    }

    float sum = 0.f, acc = 0.f;
    #pragma unroll
    for (int ki = 0; ki < KK; ++ki) {
        int dy = ki / KW, dx = ki % KW;
        float e = __expf(tt[ki] - m);
        sum += e;
        acc = fmaf(e, vs[ty + dy][tx + dx], acc);
    }

    out[((size_t)b * FC + f) * HW + hh * W + ww] = acc / sum + bias[f];
}

// ---------------------------------------------------------------------------
extern "C" void kernel_launch(void* const* d_in, const int* in_sizes, int n_in,
                              void* d_out, int out_size, void* d_ws, size_t ws_size,
                              hipStream_t stream)
{
    const float* x     = (const float*)d_in[0];
    const float* Wq    = (const float*)d_in[1];
    const float* Wk    = (const float*)d_in[2];
    const float* Wv    = (const float*)d_in[3];
    const float* rel_x = (const float*)d_in[4];
    const float* rel_y = (const float*)d_in[5];
    const float* bias  = (const float*)d_in[6];
    float* out = (float*)d_out;

    ushort* Xt  = (ushort*)d_ws;                  // 4*1024*256 bf16 = 2 MB
    ushort* Wtp = Xt + (size_t)4 * HW * C;        // 3*256*256  bf16 = 384 KB
    ushort* q   = Wtp + (size_t)3 * FC * C;       // 2 MB each
    ushort* kk  = q + (size_t)4 * FC * HW;
    ushort* vv  = kk + (size_t)4 * FC * HW;

    prep_kernel<<<304, 256, 0, stream>>>(x, Wq, Wk, Wv, Xt, Wtp);
    qkv_mfma_kernel<<<dim3(16, 8, 4), 256, 0, stream>>>(Xt, Wtp, q, kk, vv);
    attn_kernel<<<dim3(4, FC, 4), 256, 0, stream>>>(q, kk, vv, rel_x, rel_y, bias, out);
}

// Round 5
// 32.289 us; speedup vs baseline: 1.6346x; 1.1496x over previous
//
#include <hip/hip_runtime.h>
#include <math.h>

#define C   256
#define FC  256
#define H   32
#define W   32
#define HW  1024
#define KH  7
#define KW  7
#define PAD 3
#define KK  49

typedef short s16x8 __attribute__((ext_vector_type(8)));
typedef float f32x4 __attribute__((ext_vector_type(4)));

__device__ __forceinline__ ushort f2bf(float f) {
    uint u = __float_as_uint(f);
    u += 0x7FFFu + ((u >> 16) & 1u);       // round-to-nearest-even
    return (ushort)(u >> 16);
}
__device__ __forceinline__ float bf2f(ushort u) {
    return __uint_as_float(((uint)u) << 16);
}
__device__ __forceinline__ s16x8 pack8(const float* v) {
    s16x8 r;
    #pragma unroll
    for (int j = 0; j < 8; ++j) r[j] = (short)f2bf(v[j]);
    return r;
}

// ---------------------------------------------------------------------------
// Kernel 1: fused q/k/v projection via bf16 MFMA, DIRECT from x/W (no prep!).
// Grid (16 pxt, 8 fg, 4 b) = 512 blocks (2/CU), 256 thr. Wave: 16f x 32px.
// Fragments are built by per-lane strided global loads:
//   A lane l: W[c + 0..7][fbase + (l&15)]  -> 16 consecutive f x 4B = 64B line
//   B lane l: x[b][c + 0..7][px]           -> 16 consecutive px x 4B = 64B line
// i.e. each wave-load is 4 fully-utilized 64B lines; the cache does the
// transpose. No LDS. Arithmetic identical to R4 (same f2bf rounding).
// ---------------------------------------------------------------------------
__global__ __launch_bounds__(256) void qkv_direct_kernel(
    const float* __restrict__ x,  const float* __restrict__ Wq,
    const float* __restrict__ Wk, const float* __restrict__ Wv,
    ushort* __restrict__ qo, ushort* __restrict__ ko, ushort* __restrict__ vo)
{
    const int t   = threadIdx.x;
    const int pxt = blockIdx.x;        // 0..15
    const int fg  = blockIdx.y;        // 0..7
    const int b   = blockIdx.z;        // 0..3

    const int wid = t >> 6, lane = t & 63;
    const int wf = wid >> 1, wp = wid & 1;
    const int lr = lane & 15;              // A: f col / B: px col
    const int g  = lane >> 4;              // k-subgroup 0..3 (8 c each)
    const int fbase = fg * 32 + wf * 16;
    const int px0   = pxt * 64 + wp * 32 + lr;   // B frag0 col; frag1 = +16

    // base pointers at c = g*8
    const float* wqp = Wq + (size_t)(g * 8) * FC + fbase + lr;
    const float* wkp = Wk + (size_t)(g * 8) * FC + fbase + lr;
    const float* wvp = Wv + (size_t)(g * 8) * FC + fbase + lr;
    const float* xp0 = x + ((size_t)b * C + g * 8) * HW + px0;
    const float* xp1 = xp0 + 16;

    f32x4 acc00 = {0.f,0.f,0.f,0.f}, acc01 = {0.f,0.f,0.f,0.f};
    f32x4 acc10 = {0.f,0.f,0.f,0.f}, acc11 = {0.f,0.f,0.f,0.f};
    f32x4 acc20 = {0.f,0.f,0.f,0.f}, acc21 = {0.f,0.f,0.f,0.f};

    #pragma unroll
    for (int kk = 0; kk < 8; ++kk) {
        const int co = kk * 32;            // c offset of this k-step
        float aq[8], ak[8], av[8], b0[8], b1[8];
        #pragma unroll
        for (int j = 0; j < 8; ++j) {
            aq[j] = wqp[(size_t)(co + j) * FC];
            ak[j] = wkp[(size_t)(co + j) * FC];
            av[j] = wvp[(size_t)(co + j) * FC];
            b0[j] = xp0[(size_t)(co + j) * HW];
            b1[j] = xp1[(size_t)(co + j) * HW];
        }
        s16x8 A0 = pack8(aq), A1 = pack8(ak), A2 = pack8(av);
        s16x8 B0 = pack8(b0), B1 = pack8(b1);
        acc00 = __builtin_amdgcn_mfma_f32_16x16x32_bf16(A0, B0, acc00, 0, 0, 0);
        acc01 = __builtin_amdgcn_mfma_f32_16x16x32_bf16(A0, B1, acc01, 0, 0, 0);
        acc10 = __builtin_amdgcn_mfma_f32_16x16x32_bf16(A1, B0, acc10, 0, 0, 0);
        acc11 = __builtin_amdgcn_mfma_f32_16x16x32_bf16(A1, B1, acc11, 0, 0, 0);
        acc20 = __builtin_amdgcn_mfma_f32_16x16x32_bf16(A2, B0, acc20, 0, 0, 0);
        acc21 = __builtin_amdgcn_mfma_f32_16x16x32_bf16(A2, B1, acc21, 0, 0, 0);
    }

    const int fg4 = g * 4;                 // C/D: row=(lane>>4)*4+j, col=lane&15
    #pragma unroll
    for (int j = 0; j < 4; ++j) {
        size_t ro = ((size_t)(b * FC + fbase + fg4 + j)) * HW + px0;
        qo[ro]      = f2bf(acc00[j]);
        qo[ro + 16] = f2bf(acc01[j]);
        ko[ro]      = f2bf(acc10[j]);
        ko[ro + 16] = f2bf(acc11[j]);
        vo[ro]      = f2bf(acc20[j]);
        vo[ro + 16] = f2bf(acc21[j]);
    }
}

// ---------------------------------------------------------------------------
// Kernel 2: per-channel windowed softmax attention (unchanged — control).
// ---------------------------------------------------------------------------
__global__ __launch_bounds__(256) void attn_kernel(
    const ushort* __restrict__ q, const ushort* __restrict__ k,
    const ushort* __restrict__ v,
    const float* __restrict__ rel_x, const float* __restrict__ rel_y,
    const float* __restrict__ bias, float* __restrict__ out)
{
    __shared__ float ks[22][22];
    __shared__ float vs[22][22];
    __shared__ float rel_s[KK];

    const int b   = blockIdx.z;
    const int f   = blockIdx.y;
    const int th0 = (blockIdx.x >> 1) * 16;
    const int tw0 = (blockIdx.x & 1) * 16;
    const int tid = threadIdx.x;
    const int tx  = tid & 15;
    const int ty  = tid >> 4;

    if (tid < KK) {
        int dy = tid / KW, dx = tid % KW;
        rel_s[tid] = (f < 128) ? rel_x[dx * 128 + f]
                               : rel_y[dy * 128 + (f - 128)];
    }

    const ushort* kb = k + ((size_t)b * FC + f) * HW;
    const ushort* vb = v + ((size_t)b * FC + f) * HW;
    for (int i = tid; i < 22 * 22; i += 256) {
        int r = i / 22, c2 = i % 22;
        int hh = th0 - PAD + r;
        int ww = tw0 - PAD + c2;
        bool in = (hh >= 0) & (hh < H) & (ww >= 0) & (ww < W);
        ks[r][c2] = in ? bf2f(kb[hh * W + ww]) : 0.f;
        vs[r][c2] = in ? bf2f(vb[hh * W + ww]) : 0.f;
    }
    __syncthreads();

    const int hh = th0 + ty, ww = tw0 + tx;
    const float qv = bf2f(q[((size_t)b * FC + f) * HW + hh * W + ww]);

    float tt[KK];
    float m = -INFINITY;
    #pragma unroll
    for (int ki = 0; ki < KK; ++ki) {
        int dy = ki / KW, dx = ki % KW;
        float s = qv * (ks[ty + dy][tx + dx] + rel_s[ki]);
        tt[ki] = s;
        m = fmaxf(m, s);
    }

    float sum = 0.f, acc = 0.f;
    #pragma unroll
    for (int ki = 0; ki < KK; ++ki) {
        int dy = ki / KW, dx = ki % KW;
        float e = __expf(tt[ki] - m);
        sum += e;
        acc = fmaf(e, vs[ty + dy][tx + dx], acc);
    }

    out[((size_t)b * FC + f) * HW + hh * W + ww] = acc / sum + bias[f];
}

// ---------------------------------------------------------------------------
extern "C" void kernel_launch(void* const* d_in, const int* in_sizes, int n_in,
                              void* d_out, int out_size, void* d_ws, size_t ws_size,
                              hipStream_t stream)
{
    const float* x     = (const float*)d_in[0];
    const float* Wq    = (const float*)d_in[1];
    const float* Wk    = (const float*)d_in[2];
    const float* Wv    = (const float*)d_in[3];
    const float* rel_x = (const float*)d_in[4];
    const float* rel_y = (const float*)d_in[5];
    const float* bias  = (const float*)d_in[6];
    float* out = (float*)d_out;

    ushort* q  = (ushort*)d_ws;                   // 4*256*1024 bf16 = 2 MB each
    ushort* kk = q  + (size_t)4 * FC * HW;
    ushort* vv = kk + (size_t)4 * FC * HW;

    qkv_direct_kernel<<<dim3(16, 8, 4), 256, 0, stream>>>(x, Wq, Wk, Wv, q, kk, vv);
    attn_kernel<<<dim3(4, FC, 4), 256, 0, stream>>>(q, kk, vv, rel_x, rel_y, bias, out);
}